// Round 1
// baseline (4716.206 us; speedup 1.0000x reference)
//
#include <hip/hip_runtime.h>
#include <cstddef>
#include <cstdint>

#define D_EMB   1408
#define NHEADS  16
#define HD      88
#define BATCH   16
#define SEQ     577
#define M_ROWS  (BATCH * SEQ)   // 9232
#define N_QKV   (3 * D_EMB)     // 4224
#define ATT_SCALE 0.10660035817780521f  // 88^-0.5

// ---------------------------------------------------------------------------
// GEMM: C[M,N] = A[M,K] @ B[K,N] + bias[N]   (fp32, row-major)
// 128x128 block tile, BK=16, 256 threads, 8x8 micro-tile per thread.
// ---------------------------------------------------------------------------
#define BM  128
#define BN  128
#define BKK 16

__global__ __launch_bounds__(256)
void gemm_bias_kernel(const float* __restrict__ A, const float* __restrict__ B,
                      const float* __restrict__ bias, float* __restrict__ C,
                      int M, int N, int K) {
  __shared__ float As[BKK][BM];   // transposed A tile: As[k][m]
  __shared__ float Bs[BKK][BN];   // Bs[k][n]
  const int tid = threadIdx.x;
  const int bm0 = blockIdx.y * BM;
  const int bn0 = blockIdx.x * BN;
  const int tm  = (tid >> 4) * 8;   // 0..120
  const int tn  = (tid & 15) * 8;   // 0..120

  float acc[8][8];
#pragma unroll
  for (int i = 0; i < 8; ++i)
#pragma unroll
    for (int j = 0; j < 8; ++j) acc[i][j] = 0.f;

  for (int k0 = 0; k0 < K; k0 += BKK) {
    // Stage A tile (128 rows x 16 k), transpose into As[k][m]. 2 float4/thread.
#pragma unroll
    for (int i = 0; i < 2; ++i) {
      int f    = tid + i * 256;        // 0..511
      int row  = f >> 2;               // 0..127
      int kc   = (f & 3) << 2;         // 0,4,8,12
      int grow = bm0 + row;
      float4 v = make_float4(0.f, 0.f, 0.f, 0.f);
      if (grow < M) v = *(const float4*)(A + (size_t)grow * K + k0 + kc);
      As[kc + 0][row] = v.x; As[kc + 1][row] = v.y;
      As[kc + 2][row] = v.z; As[kc + 3][row] = v.w;
    }
    // Stage B tile (16 k x 128 n). 2 float4/thread, direct layout.
#pragma unroll
    for (int i = 0; i < 2; ++i) {
      int f  = tid + i * 256;          // 0..511
      int kr = f >> 5;                 // 0..15
      int nc = (f & 31) << 2;          // 0..124
      *(float4*)(&Bs[kr][nc]) = *(const float4*)(B + (size_t)(k0 + kr) * N + bn0 + nc);
    }
    __syncthreads();

#pragma unroll
    for (int kk = 0; kk < BKK; ++kk) {
      float4 a0 = *(const float4*)(&As[kk][tm]);
      float4 a1 = *(const float4*)(&As[kk][tm + 4]);
      float4 b0 = *(const float4*)(&Bs[kk][tn]);
      float4 b1 = *(const float4*)(&Bs[kk][tn + 4]);
      float av[8] = {a0.x, a0.y, a0.z, a0.w, a1.x, a1.y, a1.z, a1.w};
      float bv[8] = {b0.x, b0.y, b0.z, b0.w, b1.x, b1.y, b1.z, b1.w};
#pragma unroll
      for (int i = 0; i < 8; ++i)
#pragma unroll
        for (int j = 0; j < 8; ++j)
          acc[i][j] = fmaf(av[i], bv[j], acc[i][j]);
    }
    __syncthreads();
  }

  // Epilogue: add bias, guarded store.
#pragma unroll
  for (int i = 0; i < 8; ++i) {
    int grow = bm0 + tm + i;
    if (grow < M) {
#pragma unroll
      for (int j = 0; j < 8; j += 4) {
        float4 o;
        o.x = acc[i][j + 0] + bias[bn0 + tn + j + 0];
        o.y = acc[i][j + 1] + bias[bn0 + tn + j + 1];
        o.z = acc[i][j + 2] + bias[bn0 + tn + j + 2];
        o.w = acc[i][j + 3] + bias[bn0 + tn + j + 3];
        *(float4*)(C + (size_t)grow * N + bn0 + tn + j) = o;
      }
    }
  }
}

// ---------------------------------------------------------------------------
// Flash-style attention: one workgroup per (b, h, 32-query tile).
// qkv layout: [B*S, 4224] with [q | k | v], head h at offset h*88.
// Online softmax over K-tiles of 32. Output: attn_out [B*S, 1408].
// ---------------------------------------------------------------------------
__global__ __launch_bounds__(256)
void attn_kernel(const float* __restrict__ qkv, float* __restrict__ attn_out) {
  const int qt  = blockIdx.x;   // 0..18
  const int h   = blockIdx.y;   // 0..15
  const int b   = blockIdx.z;   // 0..15
  const int tid = threadIdx.x;

  __shared__ float Qs[32][HD + 1];   // pad to 89 to break bank aliasing
  __shared__ float Ks[32][HD + 1];
  __shared__ float Vs[32][HD + 1];
  __shared__ float Ss[32][33];
  __shared__ float mrow[32], lrow[32], arow[32];

  const int r  = tid >> 3;          // O-row this thread owns (0..31)
  const int cg = (tid & 7) * 11;    // O-col group start (11 cols, 8*11=88)

  float Oacc[11];
#pragma unroll
  for (int i = 0; i < 11; ++i) Oacc[i] = 0.f;
  if (tid < 32) { mrow[tid] = -INFINITY; lrow[tid] = 0.f; }

  const int q0 = qt * 32;
  // Load Q tile (zero-fill invalid rows).
  for (int idx = tid; idx < 32 * HD; idx += 256) {
    int rr = idx / HD, cc = idx % HD;
    int s = q0 + rr;
    Qs[rr][cc] = (s < SEQ)
        ? qkv[((size_t)(b * SEQ + s)) * N_QKV + h * HD + cc] : 0.f;
  }
  __syncthreads();

  for (int kt = 0; kt < (SEQ + 31) / 32; ++kt) {
    const int k0 = kt * 32;
    // Load K and V tiles.
    for (int idx = tid; idx < 32 * HD; idx += 256) {
      int rr = idx / HD, cc = idx % HD;
      int s = k0 + rr;
      if (s < SEQ) {
        size_t base = ((size_t)(b * SEQ + s)) * N_QKV + h * HD + cc;
        Ks[rr][cc] = qkv[base + D_EMB];
        Vs[rr][cc] = qkv[base + 2 * D_EMB];
      } else {
        Ks[rr][cc] = 0.f;
        Vs[rr][cc] = 0.f;
      }
    }
    __syncthreads();

    // Scores: 32x32, 4 per thread.
    {
      int sr  = tid >> 3;
      int sc0 = (tid & 7) * 4;
#pragma unroll
      for (int j = 0; j < 4; ++j) {
        int sc = sc0 + j;
        float dot = 0.f;
        for (int d = 0; d < HD; ++d) dot += Qs[sr][d] * Ks[sc][d];
        Ss[sr][sc] = (k0 + sc < SEQ) ? dot * ATT_SCALE : -1e30f;
      }
    }
    __syncthreads();

    // Online softmax per row (32 threads, one row each).
    if (tid < 32) {
      float mold = mrow[tid];
      float mnew = mold;
      for (int j = 0; j < 32; ++j) mnew = fmaxf(mnew, Ss[tid][j]);
      float alpha = expf(mold - mnew);   // first tile: exp(-inf) = 0
      float lsum = 0.f;
      for (int j = 0; j < 32; ++j) {
        float p = expf(Ss[tid][j] - mnew);
        Ss[tid][j] = p;
        lsum += p;
      }
      lrow[tid] = lrow[tid] * alpha + lsum;
      mrow[tid] = mnew;
      arow[tid] = alpha;
    }
    __syncthreads();

    // O update: O[r][cg..cg+10] = O*alpha + P[r][:] @ V[:, cg..cg+10]
    {
      float al = arow[r];
#pragma unroll
      for (int i = 0; i < 11; ++i) Oacc[i] *= al;
      for (int j = 0; j < 32; ++j) {
        float p = Ss[r][j];
#pragma unroll
        for (int i = 0; i < 11; ++i) Oacc[i] = fmaf(p, Vs[j][cg + i], Oacc[i]);
      }
    }
    __syncthreads();
  }

  // Normalize and store.
  int s = q0 + r;
  if (s < SEQ) {
    float inv = 1.f / lrow[r];
    size_t base = ((size_t)(b * SEQ + s)) * D_EMB + h * HD + cg;
#pragma unroll
    for (int i = 0; i < 11; ++i) attn_out[base + i] = Oacc[i] * inv;
  }
}

// ---------------------------------------------------------------------------
extern "C" void kernel_launch(void* const* d_in, const int* in_sizes, int n_in,
                              void* d_out, int out_size, void* d_ws, size_t ws_size,
                              hipStream_t stream) {
  const float* hs    = (const float*)d_in[0];  // [16,577,1408]
  const float* wqkv  = (const float*)d_in[1];  // [1408,4224]
  const float* bqkv  = (const float*)d_in[2];  // [4224]
  const float* wproj = (const float*)d_in[3];  // [1408,1408]
  const float* bproj = (const float*)d_in[4];  // [1408]
  float* out = (float*)d_out;                  // [16,577,1408]

  // Workspace: qkv [9232,4224] fp32 (155,983,872 B) then attn [9232,1408] fp32.
  float* qkv_ws  = (float*)d_ws;
  float* attn_ws = (float*)((char*)d_ws + (size_t)M_ROWS * N_QKV * sizeof(float));

  // 1) QKV projection
  dim3 g1(N_QKV / BN, (M_ROWS + BM - 1) / BM);   // 33 x 73
  gemm_bias_kernel<<<g1, 256, 0, stream>>>(hs, wqkv, bqkv, qkv_ws,
                                           M_ROWS, N_QKV, D_EMB);
  // 2) Attention
  dim3 g2((SEQ + 31) / 32, NHEADS, BATCH);       // 19 x 16 x 16
  attn_kernel<<<g2, 256, 0, stream>>>(qkv_ws, attn_ws);
  // 3) Output projection
  dim3 g3(D_EMB / BN, (M_ROWS + BM - 1) / BM);   // 11 x 73
  gemm_bias_kernel<<<g3, 256, 0, stream>>>(attn_ws, wproj, bproj, out,
                                           M_ROWS, D_EMB, D_EMB);
}

// Round 2
// 2399.494 us; speedup vs baseline: 1.9655x; 1.9655x over previous
//
#include <hip/hip_runtime.h>
#include <cstddef>
#include <cstdint>

#define D_EMB   1408
#define NHEADS  16
#define HD      88
#define HDP     96          // head dim padded to 3 MFMA k-steps of 32
#define BATCH   16
#define SEQ     577
#define M_ROWS  (BATCH * SEQ)   // 9232
#define N_QKV   (3 * D_EMB)     // 4224
#define ATT_SCALE 0.10660035817780521f  // 88^-0.5

#define QT 64    // query rows per block
#define KT 32    // key tile

typedef __attribute__((ext_vector_type(8))) short bf16x8;
typedef __attribute__((ext_vector_type(4))) float f32x4;

static __device__ __forceinline__ unsigned short f2bf(float x) {
  union { float f; unsigned u; } v; v.f = x;
  unsigned r = v.u + 0x7fff + ((v.u >> 16) & 1);   // RNE
  return (unsigned short)(r >> 16);
}
static __device__ __forceinline__ float bf2f(unsigned short h) {
  union { unsigned u; float f; } v; v.u = ((unsigned)h) << 16;
  return v.f;
}
static __device__ __forceinline__ void split_hl(float x, unsigned short* hi, unsigned short* lo) {
  unsigned short h = f2bf(x);
  *hi = h;
  *lo = f2bf(x - bf2f(h));
}

// ---------------------------------------------------------------------------
// GEMM: C[M,N] = A[M,K] @ B[K,N] + bias[N]   (fp32, row-major) — unchanged.
// ---------------------------------------------------------------------------
#define BM  128
#define BN  128
#define BKK 16

__global__ __launch_bounds__(256)
void gemm_bias_kernel(const float* __restrict__ A, const float* __restrict__ B,
                      const float* __restrict__ bias, float* __restrict__ C,
                      int M, int N, int K) {
  __shared__ float As[BKK][BM];
  __shared__ float Bs[BKK][BN];
  const int tid = threadIdx.x;
  const int bm0 = blockIdx.y * BM;
  const int bn0 = blockIdx.x * BN;
  const int tm  = (tid >> 4) * 8;
  const int tn  = (tid & 15) * 8;

  float acc[8][8];
#pragma unroll
  for (int i = 0; i < 8; ++i)
#pragma unroll
    for (int j = 0; j < 8; ++j) acc[i][j] = 0.f;

  for (int k0 = 0; k0 < K; k0 += BKK) {
#pragma unroll
    for (int i = 0; i < 2; ++i) {
      int f    = tid + i * 256;
      int row  = f >> 2;
      int kc   = (f & 3) << 2;
      int grow = bm0 + row;
      float4 v = make_float4(0.f, 0.f, 0.f, 0.f);
      if (grow < M) v = *(const float4*)(A + (size_t)grow * K + k0 + kc);
      As[kc + 0][row] = v.x; As[kc + 1][row] = v.y;
      As[kc + 2][row] = v.z; As[kc + 3][row] = v.w;
    }
#pragma unroll
    for (int i = 0; i < 2; ++i) {
      int f  = tid + i * 256;
      int kr = f >> 5;
      int nc = (f & 31) << 2;
      *(float4*)(&Bs[kr][nc]) = *(const float4*)(B + (size_t)(k0 + kr) * N + bn0 + nc);
    }
    __syncthreads();

#pragma unroll
    for (int kk = 0; kk < BKK; ++kk) {
      float4 a0 = *(const float4*)(&As[kk][tm]);
      float4 a1 = *(const float4*)(&As[kk][tm + 4]);
      float4 b0 = *(const float4*)(&Bs[kk][tn]);
      float4 b1 = *(const float4*)(&Bs[kk][tn + 4]);
      float av[8] = {a0.x, a0.y, a0.z, a0.w, a1.x, a1.y, a1.z, a1.w};
      float bv[8] = {b0.x, b0.y, b0.z, b0.w, b1.x, b1.y, b1.z, b1.w};
#pragma unroll
      for (int i = 0; i < 8; ++i)
#pragma unroll
        for (int j = 0; j < 8; ++j)
          acc[i][j] = fmaf(av[i], bv[j], acc[i][j]);
    }
    __syncthreads();
  }

#pragma unroll
  for (int i = 0; i < 8; ++i) {
    int grow = bm0 + tm + i;
    if (grow < M) {
#pragma unroll
      for (int j = 0; j < 8; j += 4) {
        float4 o;
        o.x = acc[i][j + 0] + bias[bn0 + tn + j + 0];
        o.y = acc[i][j + 1] + bias[bn0 + tn + j + 1];
        o.z = acc[i][j + 2] + bias[bn0 + tn + j + 2];
        o.w = acc[i][j + 3] + bias[bn0 + tn + j + 3];
        *(float4*)(C + (size_t)grow * N + bn0 + tn + j) = o;
      }
    }
  }
}

// ---------------------------------------------------------------------------
// MFMA flash attention. Block = (b, h, 64-query tile); 4 waves, 16 rows/wave.
// Scores: hi/lo bf16 split (3 MFMA passes) ~ fp32 precision.
// PV: bf16 P (A-op) x hi/lo V (2 passes).
// MFMA 16x16x32 bf16 layouts (HW-verified, guide §3):
//   A: lane holds A[m = lane&15][k = (lane>>4)*8 + j], j=0..7
//   B: lane holds B-col n = lane&15, same k pattern
//   C/D: col = lane&15, row = (lane>>4)*4 + reg
// ---------------------------------------------------------------------------
__global__ __launch_bounds__(256)
void attn_mfma_kernel(const float* __restrict__ qkv, float* __restrict__ attn_out) {
  __shared__ unsigned short Qhi[QT][HDP], Qlo[QT][HDP];        // 12 KB x2
  __shared__ unsigned short Khi[KT][HDP], Klo[KT][HDP];        //  6 KB x2
  __shared__ unsigned short Vthi[HDP][KT + 8], Vtlo[HDP][KT + 8]; // 7.5 KB x2
  __shared__ unsigned short Pb[QT][KT + 8];                    //  5 KB

  const int tid  = threadIdx.x;
  const int lane = tid & 63;
  const int wv   = tid >> 6;        // wave 0..3 → q-rows wv*16..wv*16+15
  const int quad = lane >> 4;
  const int lc   = lane & 15;

  const int qt = blockIdx.x, h = blockIdx.y, b = blockIdx.z;
  const int q0 = qt * QT;

  // ---- stage Q tile (hi/lo), zero-filled OOB rows + padded d 88..95
  for (int idx = tid; idx < QT * 22; idx += 256) {
    int r = idx / 22, c4 = (idx % 22) * 4;
    int s = q0 + r;
    float4 v = make_float4(0.f, 0.f, 0.f, 0.f);
    if (s < SEQ) v = *(const float4*)(qkv + (size_t)(b * SEQ + s) * N_QKV + h * HD + c4);
    split_hl(v.x, &Qhi[r][c4 + 0], &Qlo[r][c4 + 0]);
    split_hl(v.y, &Qhi[r][c4 + 1], &Qlo[r][c4 + 1]);
    split_hl(v.z, &Qhi[r][c4 + 2], &Qlo[r][c4 + 2]);
    split_hl(v.w, &Qhi[r][c4 + 3], &Qlo[r][c4 + 3]);
  }
  for (int idx = tid; idx < QT * 8; idx += 256) {
    int r = idx >> 3, c = HD + (idx & 7);
    Qhi[r][c] = 0; Qlo[r][c] = 0;
  }

  // per-lane online-softmax state: 4 rows (quad*4+reg) of this wave's 16
  float mrow[4], lrow[4];
#pragma unroll
  for (int r = 0; r < 4; ++r) { mrow[r] = -INFINITY; lrow[r] = 0.f; }
  f32x4 oacc[6];
#pragma unroll
  for (int n = 0; n < 6; ++n) oacc[n] = (f32x4){0.f, 0.f, 0.f, 0.f};

  const int ktiles = (SEQ + KT - 1) / KT;   // 19
  for (int kt = 0; kt < ktiles; ++kt) {
    const int k0 = kt * KT;
    __syncthreads();   // prev-iter PV reads done before restaging; 1st iter: Q staged

    // ---- stage K (row-major) and V (transposed), hi/lo, zero-guarded
    for (int idx = tid; idx < KT * 22; idx += 256) {
      int j = idx / 22, c4 = (idx % 22) * 4;
      int s = k0 + j;
      float4 kv = make_float4(0.f, 0.f, 0.f, 0.f);
      float4 vv = make_float4(0.f, 0.f, 0.f, 0.f);
      if (s < SEQ) {
        size_t base = (size_t)(b * SEQ + s) * N_QKV + h * HD + c4;
        kv = *(const float4*)(qkv + base + D_EMB);
        vv = *(const float4*)(qkv + base + 2 * D_EMB);
      }
      split_hl(kv.x, &Khi[j][c4 + 0], &Klo[j][c4 + 0]);
      split_hl(kv.y, &Khi[j][c4 + 1], &Klo[j][c4 + 1]);
      split_hl(kv.z, &Khi[j][c4 + 2], &Klo[j][c4 + 2]);
      split_hl(kv.w, &Khi[j][c4 + 3], &Klo[j][c4 + 3]);
      split_hl(vv.x, &Vthi[c4 + 0][j], &Vtlo[c4 + 0][j]);
      split_hl(vv.y, &Vthi[c4 + 1][j], &Vtlo[c4 + 1][j]);
      split_hl(vv.z, &Vthi[c4 + 2][j], &Vtlo[c4 + 2][j]);
      split_hl(vv.w, &Vthi[c4 + 3][j], &Vtlo[c4 + 3][j]);
    }
    for (int idx = tid; idx < KT * 8; idx += 256) {        // K pad d 88..95
      int j = idx >> 3, c = HD + (idx & 7);
      Khi[j][c] = 0; Klo[j][c] = 0;
    }
    if (tid < 256) {                                       // Vt pad rows 88..95
      int d = HD + (tid >> 5), j = tid & 31;
      Vthi[d][j] = 0; Vtlo[d][j] = 0;
    }
    __syncthreads();

    // ---- QK^T: wave's 16 q-rows x 32 keys, hi/lo 3-product
    f32x4 sc[2];
#pragma unroll
    for (int t = 0; t < 2; ++t) {
      f32x4 a = (f32x4){0.f, 0.f, 0.f, 0.f};
#pragma unroll
      for (int ks = 0; ks < 3; ++ks) {
        bf16x8 qh = *(const bf16x8*)&Qhi[wv * 16 + lc][ks * 32 + quad * 8];
        bf16x8 ql = *(const bf16x8*)&Qlo[wv * 16 + lc][ks * 32 + quad * 8];
        bf16x8 kh = *(const bf16x8*)&Khi[t * 16 + lc][ks * 32 + quad * 8];
        bf16x8 kl = *(const bf16x8*)&Klo[t * 16 + lc][ks * 32 + quad * 8];
        a = __builtin_amdgcn_mfma_f32_16x16x32_bf16(qh, kh, a, 0, 0, 0);
        a = __builtin_amdgcn_mfma_f32_16x16x32_bf16(qh, kl, a, 0, 0, 0);
        a = __builtin_amdgcn_mfma_f32_16x16x32_bf16(ql, kh, a, 0, 0, 0);
      }
      sc[t] = a;
    }
    // scale + mask OOB keys
#pragma unroll
    for (int t = 0; t < 2; ++t) {
      int key = k0 + t * 16 + lc;
      bool valid = key < SEQ;
#pragma unroll
      for (int r = 0; r < 4; ++r)
        sc[t][r] = valid ? sc[t][r] * ATT_SCALE : -INFINITY;
    }

    // ---- online softmax (row = quad*4+reg; reduce across quad's 16 lanes)
    float alpha[4];
#pragma unroll
    for (int r = 0; r < 4; ++r) {
      float v = fmaxf(sc[0][r], sc[1][r]);
      v = fmaxf(v, __shfl_xor(v, 1));
      v = fmaxf(v, __shfl_xor(v, 2));
      v = fmaxf(v, __shfl_xor(v, 4));
      v = fmaxf(v, __shfl_xor(v, 8));
      float mnew = fmaxf(mrow[r], v);
      alpha[r] = expf(mrow[r] - mnew);      // first tile: exp(-inf)=0
      mrow[r] = mnew;
      float p0 = expf(sc[0][r] - mnew);
      float p1 = expf(sc[1][r] - mnew);
      sc[0][r] = p0; sc[1][r] = p1;
      float s = p0 + p1;
      s += __shfl_xor(s, 1);
      s += __shfl_xor(s, 2);
      s += __shfl_xor(s, 4);
      s += __shfl_xor(s, 8);
      lrow[r] = lrow[r] * alpha[r] + s;
    }
    // write P (bf16) to LDS in A-operand-friendly rows; rescale O
#pragma unroll
    for (int t = 0; t < 2; ++t)
#pragma unroll
      for (int r = 0; r < 4; ++r)
        Pb[wv * 16 + quad * 4 + r][t * 16 + lc] = f2bf(sc[t][r]);
#pragma unroll
    for (int n = 0; n < 6; ++n)
#pragma unroll
      for (int r = 0; r < 4; ++r) oacc[n][r] *= alpha[r];
    __syncthreads();   // P visible (and Vt fully staged ordering kept)

    // ---- PV: O[16 x 96] += P[16 x 32] @ V[32 x 96]
    bf16x8 pf = *(const bf16x8*)&Pb[wv * 16 + lc][quad * 8];
#pragma unroll
    for (int n = 0; n < 6; ++n) {
      bf16x8 vh = *(const bf16x8*)&Vthi[n * 16 + lc][quad * 8];
      bf16x8 vl = *(const bf16x8*)&Vtlo[n * 16 + lc][quad * 8];
      oacc[n] = __builtin_amdgcn_mfma_f32_16x16x32_bf16(pf, vh, oacc[n], 0, 0, 0);
      oacc[n] = __builtin_amdgcn_mfma_f32_16x16x32_bf16(pf, vl, oacc[n], 0, 0, 0);
    }
  }

  // ---- normalize + store (C layout: row=quad*4+r, col=lc)
#pragma unroll
  for (int r = 0; r < 4; ++r) {
    int s = q0 + wv * 16 + quad * 4 + r;
    if (s < SEQ) {
      float inv = 1.f / lrow[r];
      size_t base = (size_t)(b * SEQ + s) * D_EMB + h * HD;
#pragma unroll
      for (int n = 0; n < 6; ++n) {
        int d = n * 16 + lc;
        if (d < HD) attn_out[base + d] = oacc[n][r] * inv;
      }
    }
  }
}

// ---------------------------------------------------------------------------
extern "C" void kernel_launch(void* const* d_in, const int* in_sizes, int n_in,
                              void* d_out, int out_size, void* d_ws, size_t ws_size,
                              hipStream_t stream) {
  const float* hs    = (const float*)d_in[0];
  const float* wqkv  = (const float*)d_in[1];
  const float* bqkv  = (const float*)d_in[2];
  const float* wproj = (const float*)d_in[3];
  const float* bproj = (const float*)d_in[4];
  float* out = (float*)d_out;

  float* qkv_ws  = (float*)d_ws;
  float* attn_ws = (float*)((char*)d_ws + (size_t)M_ROWS * N_QKV * sizeof(float));

  dim3 g1(N_QKV / BN, (M_ROWS + BM - 1) / BM);
  gemm_bias_kernel<<<g1, 256, 0, stream>>>(hs, wqkv, bqkv, qkv_ws,
                                           M_ROWS, N_QKV, D_EMB);

  dim3 g2((SEQ + QT - 1) / QT, NHEADS, BATCH);   // 10 x 16 x 16
  attn_mfma_kernel<<<g2, 256, 0, stream>>>(qkv_ws, attn_ws);

  dim3 g3(D_EMB / BN, (M_ROWS + BM - 1) / BM);
  gemm_bias_kernel<<<g3, 256, 0, stream>>>(attn_ws, wproj, bproj, out,
                                           M_ROWS, D_EMB, D_EMB);
}

// Round 3
// 1187.874 us; speedup vs baseline: 3.9703x; 2.0200x over previous
//
#include <hip/hip_runtime.h>
#include <cstddef>
#include <cstdint>

#define D_EMB   1408
#define NHEADS  16
#define HD      88
#define HDP     96
#define BATCH   16
#define SEQ     577
#define M_ROWS  (BATCH * SEQ)   // 9232
#define N_QKV   (3 * D_EMB)     // 4224
#define ATT_SCALE 0.10660035817780521f

#define QT 64
#define KT 32

typedef __attribute__((ext_vector_type(8))) short bf16x8;
typedef __attribute__((ext_vector_type(4))) float f32x4;

static __device__ __forceinline__ unsigned short f2bf(float x) {
  union { float f; unsigned u; } v; v.f = x;
  unsigned r = v.u + 0x7fff + ((v.u >> 16) & 1);   // RNE
  return (unsigned short)(r >> 16);
}
static __device__ __forceinline__ float bf2f(unsigned short h) {
  union { unsigned u; float f; } v; v.u = ((unsigned)h) << 16;
  return v.f;
}
static __device__ __forceinline__ void split_hl(float x, unsigned short* hi, unsigned short* lo) {
  unsigned short h = f2bf(x);
  *hi = h;
  *lo = f2bf(x - bf2f(h));
}

// async global->LDS, 16 B per lane; lds dest = wave-uniform base + lane*16
static __device__ __forceinline__ void async16(const unsigned short* g, unsigned short* l) {
  __builtin_amdgcn_global_load_lds(
      (const __attribute__((address_space(1))) unsigned int*)g,
      (__attribute__((address_space(3))) unsigned int*)l, 16, 0, 0);
}

// ---------------------------------------------------------------------------
// Elementwise hi/lo split: X fp32 -> H,L bf16 (as ushort). n4 = n/4.
// ---------------------------------------------------------------------------
__global__ __launch_bounds__(256)
void split_kernel(const float* __restrict__ X, unsigned short* __restrict__ H,
                  unsigned short* __restrict__ L, int n4) {
  int i = blockIdx.x * 256 + threadIdx.x;
  if (i >= n4) return;
  float4 v = ((const float4*)X)[i];
  ushort4 h, l;
  split_hl(v.x, &h.x, &l.x);
  split_hl(v.y, &h.y, &l.y);
  split_hl(v.z, &h.z, &l.z);
  split_hl(v.w, &h.w, &l.w);
  ((ushort4*)H)[i] = h;
  ((ushort4*)L)[i] = l;
}

// ---------------------------------------------------------------------------
// Transpose + split: W[K][N] fp32 -> Th,Tl[N][K] bf16. 32x32 tiles, 256 thr.
// ---------------------------------------------------------------------------
__global__ __launch_bounds__(256)
void transpose_split_kernel(const float* __restrict__ W, unsigned short* __restrict__ Th,
                            unsigned short* __restrict__ Tl, int K, int N) {
  __shared__ float tile[32][33];
  const int n0 = blockIdx.x * 32, k0 = blockIdx.y * 32;
  const int tx = threadIdx.x & 31, ty = threadIdx.x >> 5;  // ty 0..7
#pragma unroll
  for (int i = 0; i < 4; ++i) {
    int k = ty + i * 8;
    tile[k][tx] = W[(size_t)(k0 + k) * N + n0 + tx];
  }
  __syncthreads();
#pragma unroll
  for (int i = 0; i < 4; ++i) {
    int n = ty + i * 8;
    float v = tile[tx][n];
    unsigned short h, l;
    split_hl(v, &h, &l);
    Th[(size_t)(n0 + n) * K + k0 + tx] = h;
    Tl[(size_t)(n0 + n) * K + k0 + tx] = l;
  }
}

// ---------------------------------------------------------------------------
// 3-product hi/lo bf16 MFMA GEMM: C[M,N] = (Ah+Al)[M,K] @ (Bh+Bl)[N,K]^T + bias
// 128x128 tile, BK=32, 4 waves (2x2), each wave 64x64 (4x4 MFMA tiles).
// MODE 0: store fp32 to Cf.  MODE 1: split-store to Ch/Cl.
// LDS blocks XOR-swizzled: phys 16B-block qp holds logical q = qp ^ (row&3).
// ---------------------------------------------------------------------------
template <int MODE>
__global__ __launch_bounds__(256)
void gemm3p_kernel(const unsigned short* __restrict__ Ah,
                   const unsigned short* __restrict__ Al,
                   const unsigned short* __restrict__ Bh,
                   const unsigned short* __restrict__ Bl,
                   const float* __restrict__ bias,
                   float* __restrict__ Cf,
                   unsigned short* __restrict__ Ch,
                   unsigned short* __restrict__ Cl,
                   int M, int N, int K) {
  __shared__ unsigned short sA[2][128 * 32];
  __shared__ unsigned short sB[2][128 * 32];
  const int tid  = threadIdx.x;
  const int lane = tid & 63;
  const int w    = tid >> 6;
  const int quad = lane >> 4, lc = lane & 15;
  const int wm = w >> 1, wn = w & 1;
  const int bm0 = blockIdx.y * 128, bn0 = blockIdx.x * 128;

  f32x4 acc[4][4];
#pragma unroll
  for (int i = 0; i < 4; ++i)
#pragma unroll
    for (int j = 0; j < 4; ++j) acc[i][j] = (f32x4){0.f, 0.f, 0.f, 0.f};

  for (int k0 = 0; k0 < K; k0 += 32) {
    __syncthreads();   // prior-iter LDS reads complete before restage
#pragma unroll
    for (int i = 0; i < 2; ++i) {
      int e0  = w * 1024 + i * 512 + lane * 8;   // element idx of lane's 16B block
      int r   = e0 >> 5;
      int qp  = (e0 >> 3) & 3;
      int qlg = qp ^ (r & 3);
      int ra  = bm0 + r; if (ra > M - 1) ra = M - 1;
      size_t ga = (size_t)ra * K + (k0 + qlg * 8);
      async16(Ah + ga, &sA[0][w * 1024 + i * 512]);
      async16(Al + ga, &sA[1][w * 1024 + i * 512]);
      size_t gb = (size_t)(bn0 + r) * K + (k0 + qlg * 8);
      async16(Bh + gb, &sB[0][w * 1024 + i * 512]);
      async16(Bl + gb, &sB[1][w * 1024 + i * 512]);
    }
    __syncthreads();   // drains vmcnt (global_load_lds) per barrier semantics

    bf16x8 fah[4], fal[4], fbh[4], fbl[4];
    const int qp = quad ^ (lc & 3);
#pragma unroll
    for (int i = 0; i < 4; ++i) {
      int rowa = wm * 64 + i * 16 + lc;
      fah[i] = *(const bf16x8*)&sA[0][rowa * 32 + qp * 8];
      fal[i] = *(const bf16x8*)&sA[1][rowa * 32 + qp * 8];
      int rowb = wn * 64 + i * 16 + lc;
      fbh[i] = *(const bf16x8*)&sB[0][rowb * 32 + qp * 8];
      fbl[i] = *(const bf16x8*)&sB[1][rowb * 32 + qp * 8];
    }
#pragma unroll
    for (int i = 0; i < 4; ++i)
#pragma unroll
      for (int j = 0; j < 4; ++j) {
        acc[i][j] = __builtin_amdgcn_mfma_f32_16x16x32_bf16(fah[i], fbh[j], acc[i][j], 0, 0, 0);
        acc[i][j] = __builtin_amdgcn_mfma_f32_16x16x32_bf16(fah[i], fbl[j], acc[i][j], 0, 0, 0);
        acc[i][j] = __builtin_amdgcn_mfma_f32_16x16x32_bf16(fal[i], fbh[j], acc[i][j], 0, 0, 0);
      }
  }

  // epilogue: C/D layout col=lc, row=quad*4+reg
#pragma unroll
  for (int j = 0; j < 4; ++j) {
    int col = bn0 + wn * 64 + j * 16 + lc;
    float bj = bias[col];
#pragma unroll
    for (int i = 0; i < 4; ++i) {
#pragma unroll
      for (int rg = 0; rg < 4; ++rg) {
        int row = bm0 + wm * 64 + i * 16 + quad * 4 + rg;
        if (row < M) {
          float v = acc[i][j][rg] + bj;
          if (MODE == 0) {
            Cf[(size_t)row * N + col] = v;
          } else {
            unsigned short hh, ll;
            split_hl(v, &hh, &ll);
            Ch[(size_t)row * N + col] = hh;
            Cl[(size_t)row * N + col] = ll;
          }
        }
      }
    }
  }
}

// ---------------------------------------------------------------------------
// MFMA flash attention, hi/lo bf16 inputs pre-split (from GEMM1 epilogue).
// Block = (b, h, 64-query tile); 4 waves, 16 q-rows/wave. Writes attn hi/lo.
// ---------------------------------------------------------------------------
__global__ __launch_bounds__(256)
void attn_mfma_kernel(const unsigned short* __restrict__ qkvh,
                      const unsigned short* __restrict__ qkvl,
                      unsigned short* __restrict__ outh,
                      unsigned short* __restrict__ outl) {
  __shared__ unsigned short Qhi[QT][HDP], Qlo[QT][HDP];
  __shared__ unsigned short Khi[KT][HDP], Klo[KT][HDP];
  __shared__ unsigned short Vthi[HDP][KT + 8], Vtlo[HDP][KT + 8];
  __shared__ unsigned short Pb[QT][KT + 8];

  const int tid  = threadIdx.x;
  const int lane = tid & 63;
  const int wv   = tid >> 6;
  const int quad = lane >> 4;
  const int lc   = lane & 15;

  const int qt = blockIdx.x, h = blockIdx.y, b = blockIdx.z;
  const int q0 = qt * QT;

  for (int idx = tid; idx < QT * 22; idx += 256) {
    int r = idx / 22, c4 = (idx % 22) * 4;
    int s = q0 + r;
    ushort4 hv = make_ushort4(0, 0, 0, 0), lv = make_ushort4(0, 0, 0, 0);
    if (s < SEQ) {
      size_t base = (size_t)(b * SEQ + s) * N_QKV + h * HD + c4;
      hv = *(const ushort4*)(qkvh + base);
      lv = *(const ushort4*)(qkvl + base);
    }
    *(ushort4*)&Qhi[r][c4] = hv;
    *(ushort4*)&Qlo[r][c4] = lv;
  }
  for (int idx = tid; idx < QT * 8; idx += 256) {
    int r = idx >> 3, c = HD + (idx & 7);
    Qhi[r][c] = 0; Qlo[r][c] = 0;
  }

  float mrow[4], lrow[4];
#pragma unroll
  for (int r = 0; r < 4; ++r) { mrow[r] = -INFINITY; lrow[r] = 0.f; }
  f32x4 oacc[6];
#pragma unroll
  for (int n = 0; n < 6; ++n) oacc[n] = (f32x4){0.f, 0.f, 0.f, 0.f};

  const int ktiles = (SEQ + KT - 1) / KT;
  for (int kt = 0; kt < ktiles; ++kt) {
    const int k0 = kt * KT;
    __syncthreads();

    for (int idx = tid; idx < KT * 22; idx += 256) {
      int j = idx / 22, c4 = (idx % 22) * 4;
      int s = k0 + j;
      ushort4 kh = make_ushort4(0, 0, 0, 0), kl = make_ushort4(0, 0, 0, 0);
      ushort4 vh = make_ushort4(0, 0, 0, 0), vl = make_ushort4(0, 0, 0, 0);
    if (s < SEQ) {
        size_t base = (size_t)(b * SEQ + s) * N_QKV + h * HD + c4;
        kh = *(const ushort4*)(qkvh + base + D_EMB);
        kl = *(const ushort4*)(qkvl + base + D_EMB);
        vh = *(const ushort4*)(qkvh + base + 2 * D_EMB);
        vl = *(const ushort4*)(qkvl + base + 2 * D_EMB);
      }
      *(ushort4*)&Khi[j][c4] = kh;
      *(ushort4*)&Klo[j][c4] = kl;
      Vthi[c4 + 0][j] = vh.x; Vthi[c4 + 1][j] = vh.y;
      Vthi[c4 + 2][j] = vh.z; Vthi[c4 + 3][j] = vh.w;
      Vtlo[c4 + 0][j] = vl.x; Vtlo[c4 + 1][j] = vl.y;
      Vtlo[c4 + 2][j] = vl.z; Vtlo[c4 + 3][j] = vl.w;
    }
    for (int idx = tid; idx < KT * 8; idx += 256) {
      int j = idx >> 3, c = HD + (idx & 7);
      Khi[j][c] = 0; Klo[j][c] = 0;
    }
    {
      int d = HD + (tid >> 5), j = tid & 31;
      Vthi[d][j] = 0; Vtlo[d][j] = 0;
    }
    __syncthreads();

    f32x4 sc[2];
#pragma unroll
    for (int t = 0; t < 2; ++t) {
      f32x4 a = (f32x4){0.f, 0.f, 0.f, 0.f};
#pragma unroll
      for (int ks = 0; ks < 3; ++ks) {
        bf16x8 qh = *(const bf16x8*)&Qhi[wv * 16 + lc][ks * 32 + quad * 8];
        bf16x8 ql = *(const bf16x8*)&Qlo[wv * 16 + lc][ks * 32 + quad * 8];
        bf16x8 kh = *(const bf16x8*)&Khi[t * 16 + lc][ks * 32 + quad * 8];
        bf16x8 kl = *(const bf16x8*)&Klo[t * 16 + lc][ks * 32 + quad * 8];
        a = __builtin_amdgcn_mfma_f32_16x16x32_bf16(qh, kh, a, 0, 0, 0);
        a = __builtin_amdgcn_mfma_f32_16x16x32_bf16(qh, kl, a, 0, 0, 0);
        a = __builtin_amdgcn_mfma_f32_16x16x32_bf16(ql, kh, a, 0, 0, 0);
      }
      sc[t] = a;
    }
#pragma unroll
    for (int t = 0; t < 2; ++t) {
      int key = k0 + t * 16 + lc;
      bool valid = key < SEQ;
#pragma unroll
      for (int r = 0; r < 4; ++r)
        sc[t][r] = valid ? sc[t][r] * ATT_SCALE : -INFINITY;
    }

    float alpha[4];
#pragma unroll
    for (int r = 0; r < 4; ++r) {
      float v = fmaxf(sc[0][r], sc[1][r]);
      v = fmaxf(v, __shfl_xor(v, 1));
      v = fmaxf(v, __shfl_xor(v, 2));
      v = fmaxf(v, __shfl_xor(v, 4));
      v = fmaxf(v, __shfl_xor(v, 8));
      float mnew = fmaxf(mrow[r], v);
      alpha[r] = expf(mrow[r] - mnew);
      mrow[r] = mnew;
      float p0 = expf(sc[0][r] - mnew);
      float p1 = expf(sc[1][r] - mnew);
      sc[0][r] = p0; sc[1][r] = p1;
      float s = p0 + p1;
      s += __shfl_xor(s, 1);
      s += __shfl_xor(s, 2);
      s += __shfl_xor(s, 4);
      s += __shfl_xor(s, 8);
      lrow[r] = lrow[r] * alpha[r] + s;
    }
#pragma unroll
    for (int t = 0; t < 2; ++t)
#pragma unroll
      for (int r = 0; r < 4; ++r)
        Pb[wv * 16 + quad * 4 + r][t * 16 + lc] = f2bf(sc[t][r]);
#pragma unroll
    for (int n = 0; n < 6; ++n)
#pragma unroll
      for (int r = 0; r < 4; ++r) oacc[n][r] *= alpha[r];
    __syncthreads();

    bf16x8 pf = *(const bf16x8*)&Pb[wv * 16 + lc][quad * 8];
#pragma unroll
    for (int n = 0; n < 6; ++n) {
      bf16x8 vh = *(const bf16x8*)&Vthi[n * 16 + lc][quad * 8];
      bf16x8 vl = *(const bf16x8*)&Vtlo[n * 16 + lc][quad * 8];
      oacc[n] = __builtin_amdgcn_mfma_f32_16x16x32_bf16(pf, vh, oacc[n], 0, 0, 0);
      oacc[n] = __builtin_amdgcn_mfma_f32_16x16x32_bf16(pf, vl, oacc[n], 0, 0, 0);
    }
  }

#pragma unroll
  for (int r = 0; r < 4; ++r) {
    int s = q0 + wv * 16 + quad * 4 + r;
    if (s < SEQ) {
      float inv = 1.f / lrow[r];
      size_t base = (size_t)(b * SEQ + s) * D_EMB + h * HD;
#pragma unroll
      for (int n = 0; n < 6; ++n) {
        int d = n * 16 + lc;
        if (d < HD) {
          float v = oacc[n][r] * inv;
          unsigned short hh, ll;
          split_hl(v, &hh, &ll);
          outh[base + d] = hh;
          outl[base + d] = ll;
        }
      }
    }
  }
}

// ---------------------------------------------------------------------------
extern "C" void kernel_launch(void* const* d_in, const int* in_sizes, int n_in,
                              void* d_out, int out_size, void* d_ws, size_t ws_size,
                              hipStream_t stream) {
  const float* hs    = (const float*)d_in[0];
  const float* wqkv  = (const float*)d_in[1];
  const float* bqkv  = (const float*)d_in[2];
  const float* wproj = (const float*)d_in[3];
  const float* bproj = (const float*)d_in[4];
  float* out = (float*)d_out;

  // workspace layout (bf16 as ushort):
  //  qkvH, qkvL    : [9232][4224]  (156.0 MB total)
  //  hsH/attnH, hsL/attnL : [9232][1408] (aliased; 52.0 MB total)
  //  wtH, wtL      : [4224][1408]  (23.8 MB total; reused for wproj^T)
  unsigned short* qkvH = (unsigned short*)d_ws;
  unsigned short* qkvL = qkvH + (size_t)M_ROWS * N_QKV;
  unsigned short* hsH  = qkvL + (size_t)M_ROWS * N_QKV;
  unsigned short* hsL  = hsH + (size_t)M_ROWS * D_EMB;
  unsigned short* wtH  = hsL + (size_t)M_ROWS * D_EMB;
  unsigned short* wtL  = wtH + (size_t)N_QKV * D_EMB;
  unsigned short* attnH = hsH;   // alias: hs dead after GEMM1
  unsigned short* attnL = hsL;

  // 1) split hidden_states
  {
    int n4 = (M_ROWS * D_EMB) / 4;
    split_kernel<<<(n4 + 255) / 256, 256, 0, stream>>>(hs, hsH, hsL, n4);
  }
  // 2) transpose+split w_qkv: [1408][4224] -> [4224][1408]
  {
    dim3 g(N_QKV / 32, D_EMB / 32);
    transpose_split_kernel<<<g, 256, 0, stream>>>(wqkv, wtH, wtL, D_EMB, N_QKV);
  }
  // 3) QKV GEMM -> qkv hi/lo (bias fused)
  {
    dim3 g(N_QKV / 128, (M_ROWS + 127) / 128);   // 33 x 73
    gemm3p_kernel<1><<<g, 256, 0, stream>>>(hsH, hsL, wtH, wtL, bqkv,
                                            nullptr, qkvH, qkvL,
                                            M_ROWS, N_QKV, D_EMB);
  }
  // 4) attention -> attn hi/lo (aliases hs region; safe: same-stream ordering)
  {
    dim3 g((SEQ + QT - 1) / QT, NHEADS, BATCH);
    attn_mfma_kernel<<<g, 256, 0, stream>>>(qkvH, qkvL, attnH, attnL);
  }
  // 5) transpose+split w_proj into wt region (dead after GEMM1)
  {
    dim3 g(D_EMB / 32, D_EMB / 32);
    transpose_split_kernel<<<g, 256, 0, stream>>>(wproj, wtH, wtL, D_EMB, D_EMB);
  }
  // 6) output projection -> fp32 out (bias fused)
  {
    dim3 g(D_EMB / 128, (M_ROWS + 127) / 128);   // 11 x 73
    gemm3p_kernel<0><<<g, 256, 0, stream>>>(attnH, attnL, wtH, wtL, bproj,
                                            out, nullptr, nullptr,
                                            M_ROWS, D_EMB, D_EMB);
  }
}